// Round 2
// 133.522 us; speedup vs baseline: 1.0029x; 1.0029x over previous
//
#include <hip/hip_runtime.h>
#include <hip/hip_fp16.h>

#define NH  16
#define SQL 1024
#define SKV 4096
#define HD  128
#define TK  64

typedef _Float16 h2_t __attribute__((ext_vector_type(2)));
typedef float    f32x4 __attribute__((ext_vector_type(4)));   // nontemporal-safe

__device__ __forceinline__ unsigned pkh(float x, float y) {
    return (unsigned)__half_as_ushort(__float2half(x)) |
           ((unsigned)__half_as_ushort(__float2half(y)) << 16);
}

// ---- fp32 -> fp16 streaming cast, layout preserved [H][SKV][HD] ----
// blocks [0,4096): K, [4096,8192): V; 8 elems/thread
__global__ __launch_bounds__(256) void cvt_f16(
    const float* __restrict__ k, const float* __restrict__ v,
    unsigned short* __restrict__ kh, unsigned short* __restrict__ vh)
{
    int b = blockIdx.x;
    const float* src; unsigned short* dst;
    if (b < 4096) { src = k; dst = kh; }
    else          { src = v; dst = vh; b -= 4096; }
    const size_t i = (size_t)b * 256 + threadIdx.x;   // 8-elem chunk
    const float4* s4 = (const float4*)src;
    float4 a = s4[2 * i], c = s4[2 * i + 1];
    uint4 o;
    o.x = pkh(a.x, a.y);
    o.y = pkh(a.z, a.w);
    o.z = pkh(c.x, c.y);
    o.w = pkh(c.z, c.w);
    ((uint4*)dst)[i] = o;
}

// ---- phase-separated attention:
// grid 512 blocks (2/CU, co-resident). Block b -> XCD b&7.
// Round 0: head b&7, round 1: head (b&7)+8  => one head per XCD at a time.
// Within a round: phase A = K-gathers + softmax for 4 queries/wave
// (weights kept in registers), barrier, phase B = V-gathers + PV.
// Per-XCD active gather set per phase = 2.1 MB fp16 -> fully L2-resident
// (vs 4.2 MB K+V interleaved before, which oversubscribed the 4 MB L2).
__global__ __launch_bounds__(256, 2) void dsa_phased(
    const float* __restrict__ q, const unsigned short* __restrict__ kh,
    const unsigned short* __restrict__ vh, const int* __restrict__ tidx,
    const float* __restrict__ tsc, float* __restrict__ out)
{
    __shared__ float scr[4][TK][17];   // transpose buffer; wave-private rows

    const int tid  = threadIdx.x;
    const int wv   = tid >> 6;
    const int lane = tid & 63;
    const int quad = lane >> 4;    // which of 4 gathered rows this 16-lane group loads
    const int l16  = lane & 15;    // dims 8*l16 .. 8*l16+7
    const int bi   = blockIdx.x;
    const int xcd  = bi & 7;
    const int tile = bi >> 3;              // 0..63, 16 queries per tile
    const int sb   = tile * 16 + wv * 4;   // first of this wave's 4 queries

    // topk idx/scores are head-independent: load once, reuse both rounds
    int   tIdx[4];
    float tSc[4];
#pragma unroll
    for (int qi = 0; qi < 4; ++qi) {
        tIdx[qi] = tidx[(sb + qi) * TK + lane];
        tSc[qi]  = tsc[(sb + qi) * TK + lane];
    }

    for (int rnd = 0; rnd < 2; ++rnd) {
        const int h = xcd | (rnd << 3);
        const unsigned short* kb = kh + (size_t)h * SKV * HD;
        const unsigned short* vb = vh + (size_t)h * SKV * HD;
        unsigned wpk[4];   // per-query softmax weight (lane t owns t), packed half2

        // ---------------- phase A: K gathers, scores, softmax ----------------
#pragma unroll
        for (int qi = 0; qi < 4; ++qi) {
            const int s = sb + qi;
            // q fragment: 8 dims (fp32, nontemporal: don't evict K from L2)
            const float* qp = q + (size_t)(h * SQL + s) * HD + 8 * l16;
            const f32x4 qa = __builtin_nontemporal_load((const f32x4*)qp);
            const f32x4 qb = __builtin_nontemporal_load((const f32x4*)qp + 1);
            h2_t q0 = {(_Float16)qa.x, (_Float16)qa.y};
            h2_t q1 = {(_Float16)qa.z, (_Float16)qa.w};
            h2_t q2 = {(_Float16)qb.x, (_Float16)qb.y};
            h2_t q3 = {(_Float16)qb.z, (_Float16)qb.w};

            float part[16];
#pragma unroll
            for (int i = 0; i < 16; ++i) {
                const size_t row = (size_t)__shfl(tIdx[qi], 4 * i + quad);
                uint4 kw = *(const uint4*)(kb + row * HD + 8 * l16);
                float d = 0.f;
#if __has_builtin(__builtin_amdgcn_fdot2)
                d = __builtin_amdgcn_fdot2(q0, __builtin_bit_cast(h2_t, kw.x), d, false);
                d = __builtin_amdgcn_fdot2(q1, __builtin_bit_cast(h2_t, kw.y), d, false);
                d = __builtin_amdgcn_fdot2(q2, __builtin_bit_cast(h2_t, kw.z), d, false);
                d = __builtin_amdgcn_fdot2(q3, __builtin_bit_cast(h2_t, kw.w), d, false);
#else
                {
                    float2 k0 = __half22float2(__builtin_bit_cast(__half2, kw.x));
                    float2 k1 = __half22float2(__builtin_bit_cast(__half2, kw.y));
                    float2 k2 = __half22float2(__builtin_bit_cast(__half2, kw.z));
                    float2 k3 = __half22float2(__builtin_bit_cast(__half2, kw.w));
                    d  = qa.x * k0.x + qa.y * k0.y + qa.z * k1.x + qa.w * k1.y;
                    d += qb.x * k2.x + qb.y * k2.y + qb.z * k3.x + qb.w * k3.y;
                }
#endif
                part[i] = d;
            }

            // one LDS transpose (wave-private rows -> no barrier): lane j ends
            // up owning the score for t=j, exactly the softmax layout.
#pragma unroll
            for (int i = 0; i < 16; ++i) scr[wv][4 * i + quad][l16] = part[i];
            float acc = 0.f;
#pragma unroll
            for (int m = 0; m < 16; ++m) acc += scr[wv][lane][m];
            acc *= 0.08838834764831845f;                       // 1/sqrt(128)

            // fused softmax * topk_scores, renormalized:
            // w_t = e_t*ts_t / (sum(e*ts) + 1e-12*sum(e))
            float mx = acc;
#pragma unroll
            for (int off = 32; off; off >>= 1) mx = fmaxf(mx, __shfl_xor(mx, off));
            const float e   = __expf(acc - mx);
            const float ets = e * tSc[qi];
            float se = e, sets = ets;
#pragma unroll
            for (int off = 32; off; off >>= 1) {
                se   += __shfl_xor(se, off);
                sets += __shfl_xor(sets, off);
            }
            const float w = ets / (sets + 1e-12f * se);
            wpk[qi] = __builtin_bit_cast(unsigned, __float2half2_rn(w));
        }

        __syncthreads();   // keep the block's waves phase-aligned (K done, V next)

        // ---------------- phase B: V gathers + PV + store ----------------
#pragma unroll
        for (int qi = 0; qi < 4; ++qi) {
            const int s = sb + qi;
            __half2 o0 = __float2half2_rn(0.f);
            __half2 o1 = o0, o2 = o0, o3 = o0;
#pragma unroll
            for (int i = 0; i < 16; ++i) {
                const size_t row = (size_t)__shfl(tIdx[qi], 4 * i + quad);
                uint4 vw = *(const uint4*)(vb + row * HD + 8 * l16);
                const __half2 w2 =
                    __builtin_bit_cast(__half2, __shfl(wpk[qi], 4 * i + quad));
                o0 = __hfma2(w2, __builtin_bit_cast(__half2, vw.x), o0);
                o1 = __hfma2(w2, __builtin_bit_cast(__half2, vw.y), o1);
                o2 = __hfma2(w2, __builtin_bit_cast(__half2, vw.z), o2);
                o3 = __hfma2(w2, __builtin_bit_cast(__half2, vw.w), o3);
            }

            // quads hold disjoint t-subsets of the same dims -> combine fp16 pairs
            __half2 oo[4] = {o0, o1, o2, o3};
#pragma unroll
            for (int j = 0; j < 4; ++j) {
                unsigned u = __builtin_bit_cast(unsigned, oo[j]);
                oo[j] = __hadd2(oo[j], __builtin_bit_cast(__half2, __shfl_xor(u, 16)));
                u = __builtin_bit_cast(unsigned, oo[j]);
                oo[j] = __hadd2(oo[j], __builtin_bit_cast(__half2, __shfl_xor(u, 32)));
            }

            if (quad == 0) {
                float2 f0 = __half22float2(oo[0]);
                float2 f1 = __half22float2(oo[1]);
                float2 f2 = __half22float2(oo[2]);
                float2 f3 = __half22float2(oo[3]);
                float* op = out + (size_t)(h * SQL + s) * HD + 8 * l16;
                f32x4 w0 = {f0.x, f0.y, f1.x, f1.y};
                f32x4 w1 = {f2.x, f2.y, f3.x, f3.y};
                __builtin_nontemporal_store(w0, (f32x4*)op);
                __builtin_nontemporal_store(w1, (f32x4*)op + 1);
            }
        }
        if (rnd == 0) __syncthreads();   // don't let head x+8 K-gathers start
                                         // while head x V-phase still runs
    }
}

// ---- fp32 fallback (round-1 kernel) if workspace too small ----
__global__ __launch_bounds__(256) void dsa_fp32(
    const float* __restrict__ q, const float* __restrict__ k,
    const float* __restrict__ v, const int* __restrict__ tidx,
    const float* __restrict__ tsc, float* __restrict__ out)
{
    __shared__ int   idxs[4][TK];
    __shared__ float wsc[4][TK];
    const int tid = threadIdx.x, wv = tid >> 6, lane = tid & 63;
    const int half = lane >> 5, l32 = lane & 31, bi = blockIdx.x;
    const int h = ((bi & 7) << 1) | ((bi >> 3) & 1);
    const int s = ((bi >> 4) << 2) + wv;
    const float* qp = q + (size_t)(h * SQL + s) * HD;
    const float4 qf = *(const float4*)(qp + 4 * l32);
    const float t_sc = tsc[s * TK + lane];
    idxs[wv][lane] = tidx[s * TK + lane];
    const float* kb = k + (size_t)h * SKV * HD;
#pragma unroll 4
    for (int i = 0; i < TK / 2; ++i) {
        const int t = 2 * i + half, row = idxs[wv][t];
        float4 k4 = *(const float4*)(kb + (size_t)row * HD + 4 * l32);
        float d = k4.x * qf.x + k4.y * qf.y + k4.z * qf.z + k4.w * qf.w;
        d += __shfl_xor(d, 16); d += __shfl_xor(d, 8); d += __shfl_xor(d, 4);
        d += __shfl_xor(d, 2);  d += __shfl_xor(d, 1);
        if (l32 == 0) wsc[wv][t] = d;
    }
    float acc = wsc[wv][lane] * 0.08838834764831845f;
    float m = acc;
#pragma unroll
    for (int off = 32; off; off >>= 1) m = fmaxf(m, __shfl_xor(m, off));
    const float e = __expf(acc - m), ets = e * t_sc;
    float se = e, sets = ets;
#pragma unroll
    for (int off = 32; off; off >>= 1) { se += __shfl_xor(se, off); sets += __shfl_xor(sets, off); }
    wsc[wv][lane] = ets / (sets + 1e-12f * se);
    const float* vbp = v + (size_t)h * SKV * HD;
    float4 o = make_float4(0.f, 0.f, 0.f, 0.f);
#pragma unroll 4
    for (int i = 0; i < TK / 2; ++i) {
        const int t = 2 * i + half, row = idxs[wv][t];
        const float wt = wsc[wv][t];
        float4 v4 = *(const float4*)(vbp + (size_t)row * HD + 4 * l32);
        o.x += wt * v4.x; o.y += wt * v4.y; o.z += wt * v4.z; o.w += wt * v4.w;
    }
    o.x += __shfl_xor(o.x, 32); o.y += __shfl_xor(o.y, 32);
    o.z += __shfl_xor(o.z, 32); o.w += __shfl_xor(o.w, 32);
    if (half == 0) *(float4*)(out + (size_t)(h * SQL + s) * HD + 4 * l32) = o;
}

extern "C" void kernel_launch(void* const* d_in, const int* in_sizes, int n_in,
                              void* d_out, int out_size, void* d_ws, size_t ws_size,
                              hipStream_t stream) {
    const float* q  = (const float*)d_in[0];
    const float* k  = (const float*)d_in[1];
    const float* v  = (const float*)d_in[2];
    const int*   ti = (const int*)d_in[3];
    const float* ts = (const float*)d_in[4];
    float* out = (float*)d_out;

    const size_t nkv  = (size_t)NH * SKV * HD;            // 8.4M elems each
    const size_t need = 2 * nkv * sizeof(unsigned short); // 33.6 MB
    if (ws_size >= need) {
        unsigned short* kh = (unsigned short*)d_ws;
        unsigned short* vh = kh + nkv;
        cvt_f16<<<dim3(8192), dim3(256), 0, stream>>>(k, v, kh, vh);
        dsa_phased<<<dim3(512), dim3(256), 0, stream>>>(q, kh, vh, ti, ts, out);
    } else {
        dsa_fp32<<<dim3(4096), dim3(256), 0, stream>>>(q, k, v, ti, ts, out);
    }
}